// Round 10
// baseline (335.455 us; speedup 1.0000x reference)
//
#include <hip/hip_runtime.h>
#include <math.h>

#define TOKENS 16384
#define HIDDEN 2048
#define NEXP   64
#define MT     32                  // tokens per block
#define NBLK   (TOKENS / MT)       // 512

#define GATES_OFF (TOKENS * 2)
#define SEL_OFF   (GATES_OFF + TOKENS * NEXP)
#define Z_OFF     (SEL_OFF + TOKENS * 2)

__device__ __forceinline__ float wave_sum64(float v) {
    #pragma unroll
    for (int s = 1; s < 64; s <<= 1) v += __shfl_xor(v, s, 64);
    return v;
}

// ---------------------------------------------------------------------------
// R10: pure fp32 vector-FMA router. R3-R9 post-mortem: every MFMA structure
// (reg-pipelined, DMA-staged, barrier-free, B-shared) plateaued at
// dur ~= FETCH(67.7MB)/850GB/s -- the MFMA tile layouts never generate
// enough concurrent memory pressure (4-16 waves/CU, bursty serialized
// batches). The problem's VALU roofline is only 27us (4.3GFLOP @ 157TF fp32)
// and plain per-lane float4 streaming at high TLP is the m13-proven way to
// saturate the memory system. Structure: 512 blocks x 256 thr (2 blocks/CU,
// 8 waves/CU); wave wv takes k-slice [wv*512,+512); thread (tl=lane>>4,
// eg=lane&15) computes 8 tokens (tl*8+j) x 4 experts (eg*4+e) in 32 fp32
// accumulators. Inner k4 step: 12 float4 loads -> 128 independent FMAs.
// w: 16x16B gather/inst, L2-resident (256MB total, ~8TB/s avg). x: read
// once, 4-lane-dedup'd 16B requests. One barrier total: 4-way k-partial
// reduce via LDS [4][32][66], then the R8/R9-VERIFIED 16-wide-shuffle
// routing epilogue (e[j]=eg*4+j, consecutive-lane token groups). fp32
// everywhere -> absmax should drop vs the fp16-split path. No wconvert.
// ---------------------------------------------------------------------------
__global__ __launch_bounds__(256, 2) void router_fma(
    const float* __restrict__ x, const float* __restrict__ w,
    float* __restrict__ out, float* __restrict__ zpartial)
{
    __shared__ __align__(16) float lg[4][MT][66];    // 33792 B k-partials
    __shared__ float zred[4];

    const int tid  = threadIdx.x;
    const int wv   = __builtin_amdgcn_readfirstlane(tid >> 6);
    const int lane = tid & 63;
    const int eg   = lane & 15;          // expert group: experts eg*4..+3
    const int tl   = lane >> 4;          // token group: tokens tl*8..+7
    const int t0   = blockIdx.x * MT;

    const float* xp = x + (size_t)(t0 + tl * 8) * HIDDEN + wv * 512;
    const float* wp = w + (size_t)(eg * 4) * HIDDEN + wv * 512;

    float acc[8][4];
    #pragma unroll
    for (int j = 0; j < 8; ++j)
        #pragma unroll
        for (int e = 0; e < 4; ++e) acc[j][e] = 0.f;

    #pragma unroll 2
    for (int kk = 0; kk < 512; kk += 4) {
        float4 xv[8], wv4[4];
        #pragma unroll
        for (int j = 0; j < 8; ++j)
            xv[j] = *(const float4*)(xp + (size_t)j * HIDDEN + kk);
        #pragma unroll
        for (int e = 0; e < 4; ++e)
            wv4[e] = *(const float4*)(wp + (size_t)e * HIDDEN + kk);

        #pragma unroll
        for (int j = 0; j < 8; ++j)
            #pragma unroll
            for (int e = 0; e < 4; ++e) {
                acc[j][e] = fmaf(xv[j].x, wv4[e].x, acc[j][e]);
                acc[j][e] = fmaf(xv[j].y, wv4[e].y, acc[j][e]);
                acc[j][e] = fmaf(xv[j].z, wv4[e].z, acc[j][e]);
                acc[j][e] = fmaf(xv[j].w, wv4[e].w, acc[j][e]);
            }
    }

    // ---- k-partial reduce through LDS ----
    #pragma unroll
    for (int j = 0; j < 8; ++j)
        #pragma unroll
        for (int e = 0; e < 4; ++e)
            lg[wv][tl * 8 + j][eg * 4 + e] = acc[j][e];
    __syncthreads();

    // ---- routing epilogue [R8/R9-verified]: wave wv routes tokens
    // wv*8..+7; lanes: tt=lane>>4 picks token, eg = expert group; 2 rounds.
    float zsum = 0.f;
    const int tt = lane >> 4;
    #pragma unroll
    for (int r2 = 0; r2 < 2; ++r2) {
        const int tloc = wv * 8 + r2 * 4 + tt;
        float v[4]; int e[4];
        #pragma unroll
        for (int j = 0; j < 4; ++j) {
            v[j] = lg[0][tloc][eg * 4 + j] + lg[1][tloc][eg * 4 + j]
                 + lg[2][tloc][eg * 4 + j] + lg[3][tloc][eg * 4 + j];
            e[j] = eg * 4 + j;
        }

        // pass-1 argmax (local strict > keeps lowest e; cross-lane verified)
        float bv = v[0]; int bi = e[0];
        #pragma unroll
        for (int j = 1; j < 4; ++j)
            if (v[j] > bv) { bv = v[j]; bi = e[j]; }
        #pragma unroll
        for (int st = 1; st < 16; st <<= 1) {
            const float ov = __shfl_xor(bv, st, 64);
            const int   oi = __shfl_xor(bi, st, 64);
            if (ov > bv || (ov == bv && oi < bi)) { bv = ov; bi = oi; }
        }
        const float max1 = bv; const int s1 = bi;

        float e1[4], se = 0.f, sm1 = 0.f;
        #pragma unroll
        for (int j = 0; j < 4; ++j) {
            e1[j] = expf(v[j] - max1);
            se += e1[j];
            const bool m1 = (max1 - v[j]) > 0.02f * fmaxf(fabsf(v[j]), max1);
            sm1 += m1 ? 0.f : e1[j];
        }
        #pragma unroll
        for (int st = 1; st < 16; st <<= 1) {
            se  += __shfl_xor(se, st, 64);
            sm1 += __shfl_xor(sm1, st, 64);
        }

        // gates: 4 consecutive floats per lane -> float4 store
        {
            float4 gv;
            gv.x = e1[0] / se; gv.y = e1[1] / se;
            gv.z = e1[2] / se; gv.w = e1[3] / se;
            *(float4*)(out + GATES_OFF + (size_t)(t0 + tloc) * NEXP + eg * 4) = gv;
        }

        const float lse = max1 + logf(se);
        if (eg == 0) zsum += lse * lse;

        // pass-2 argmax with s1 masked
        float bv2 = (e[0] == s1) ? -INFINITY : v[0]; int bi2 = e[0];
        #pragma unroll
        for (int j = 1; j < 4; ++j) {
            const float cv = (e[j] == s1) ? -INFINITY : v[j];
            if (cv > bv2) { bv2 = cv; bi2 = e[j]; }
        }
        #pragma unroll
        for (int st = 1; st < 16; st <<= 1) {
            const float ov = __shfl_xor(bv2, st, 64);
            const int   oi = __shfl_xor(bi2, st, 64);
            if (ov > bv2 || (ov == bv2 && oi < bi2)) { bv2 = ov; bi2 = oi; }
        }
        const float max2 = bv2; const int s2 = bi2;

        float sm2 = 0.f;
        #pragma unroll
        for (int j = 0; j < 4; ++j) {
            const bool m2 = (max2 - v[j]) > 0.02f * fmaxf(fabsf(v[j]), max2);
            sm2 += (m2 || e[j] == s1) ? 0.f : expf(v[j] - max2);
        }
        #pragma unroll
        for (int st = 1; st < 16; st <<= 1)
            sm2 += __shfl_xor(sm2, st, 64);

        if (eg == 0) {
            const size_t trow = (size_t)(t0 + tloc) * 2;
            out[trow + 0] = 1.f / sm1;
            out[trow + 1] = 1.f / sm2;
            out[SEL_OFF + trow + 0] = (float)s1;
            out[SEL_OFF + trow + 1] = (float)s2;
        }
    }

    const float zt = wave_sum64(zsum);
    if (lane == 0) zred[wv] = zt;
    __syncthreads();
    if (tid == 0)
        zpartial[blockIdx.x] = zred[0] + zred[1] + zred[2] + zred[3];
}

__global__ __launch_bounds__(256) void zfinal(
    const float* __restrict__ zpartial, float* __restrict__ out)
{
    const int tid = threadIdx.x;                 // 512 partials, 256 threads
    float v = zpartial[tid] + zpartial[tid + 256];
    v = wave_sum64(v);
    __shared__ float red[4];
    if ((tid & 63) == 0) red[tid >> 6] = v;
    __syncthreads();
    if (tid == 0) {
        const float tot = red[0] + red[1] + red[2] + red[3];
        out[Z_OFF] = 0.001f * (tot / (float)TOKENS);
    }
}

extern "C" void kernel_launch(void* const* d_in, const int* in_sizes, int n_in,
                              void* d_out, int out_size, void* d_ws, size_t ws_size,
                              hipStream_t stream) {
    const float* x = (const float*)d_in[0];   // [16384, 2048] fp32
    const float* w = (const float*)d_in[1];   // [64, 2048] fp32
    float* out = (float*)d_out;               // mult(32768) | gates(1048576) | sel(32768) | z(1)

    float* zpartial = (float*)d_ws;           // 512 floats

    router_fma<<<NBLK, 256, 0, stream>>>(x, w, out, zpartial);
    zfinal<<<1, 256, 0, stream>>>(zpartial, out);
}

// Round 11
// 216.725 us; speedup vs baseline: 1.5478x; 1.5478x over previous
//
#include <hip/hip_runtime.h>
#include <math.h>

#define TOKENS 16384
#define HIDDEN 2048
#define NEXP   64
#define MT     64                  // tokens per block (4 waves x 16)
#define NBLK   (TOKENS / MT)       // 256 = 1 block per CU
#define CK     64                  // k floats per chunk (= one wimg chunk)
#define NCH    (HIDDEN / CK)       // 32
#define SLOT   32768               // ring slot: x 16KB + B 16KB
#define BOFF   16384               // B offset within slot

#define GATES_OFF (TOKENS * 2)
#define SEL_OFF   (GATES_OFF + TOKENS * NEXP)
#define Z_OFF     (SEL_OFF + TOKENS * 2)

#define WIMG_BYTES (NEXP * HIDDEN * 2 * 2)   // 512 KB fp16 wh+wl fragment image

typedef __attribute__((ext_vector_type(8))) _Float16 f16x8;
typedef __attribute__((ext_vector_type(4))) float    f32x4;

__device__ __forceinline__ float wave_sum64(float v) {
    #pragma unroll
    for (int s = 1; s < 64; s <<= 1) v += __shfl_xor(v, s, 64);
    return v;
}

// direct global->LDS DMA, 16 B per lane (dest = wave-uniform base + lane*16)
__device__ __forceinline__ void dma16(const void* g, void* l) {
    __builtin_amdgcn_global_load_lds(
        (const __attribute__((address_space(1))) unsigned int*)g,
        (__attribute__((address_space(3))) unsigned int*)l, 16, 0, 0);
}

// ---------------------------------------------------------------------------
// Setup: w [64,2048] fp32 -> fp16 (hi, lo*4096) fragment image. [verified R3]
// Image: [chunk 32][slot r 1024]; r = eh*512 + term*256 + kh*128 + nt*64 +
// lane; slot lane l: expert col l&15, klocal (l>>4)*8 + j.
// ---------------------------------------------------------------------------
__global__ __launch_bounds__(256) void wconvert(
    const float* __restrict__ w, uint4* __restrict__ wimg)
{
    const int s = blockIdx.x * 256 + threadIdx.x;     // 0..32767
    const int c    = s >> 10;
    const int r    = s & 1023;
    const int l    = r & 63;
    const int nt   = (r >> 6) & 1;
    const int kh   = (r >> 7) & 1;
    const int term = (r >> 8) & 1;
    const int eh   = (r >> 9) & 1;
    const int e = eh * 32 + nt * 16 + (l & 15);
    const int k = c * 64 + kh * 32 + (l >> 4) * 8;

    const float* src = w + (size_t)e * HIDDEN + k;
    union { _Float16 f[8]; uint4 u; } o;
    #pragma unroll
    for (int j = 0; j < 8; ++j) {
        const float v = src[j];
        const _Float16 h = (_Float16)v;
        o.f[j] = (term == 0) ? h : (_Float16)((v - (float)h) * 4096.f);
    }
    wimg[s] = o.u;
}

// fp32 -> (hi, lo*4096) fp16x8 split of 8 floats [verified R3]
__device__ __forceinline__ void cvt_split(const float4 a, const float4 b,
                                          f16x8& hi, f16x8& lo) {
    union { _Float16 f[8]; f16x8 v; } H, L;
    #pragma unroll
    for (int j = 0; j < 4; ++j) {
        const float s0 = (&a.x)[j];
        const float s1 = (&b.x)[j];
        const _Float16 h0 = (_Float16)s0;
        const _Float16 h1 = (_Float16)s1;
        H.f[j]     = h0;
        H.f[j + 4] = h1;
        L.f[j]     = (_Float16)((s0 - (float)h0) * 4096.f);
        L.f[j + 4] = (_Float16)((s1 - (float)h1) * 4096.f);
    }
    hi = H.v; lo = L.v;
}

// stage one chunk's quarter for wave wv: 4 x-DMA (16 rows x 256B, R8-verified
// [slab][kgslot][row][16B] layout) + 4 B-DMA (wimg slots [wv*256,+256)).
__device__ __forceinline__ void stage_chunk(
    unsigned char* smem, const float* xq, const uint4* wq, int wv, int c)
{
    unsigned char* s = smem + (size_t)(c & 3) * SLOT;
    unsigned char* xd = s + wv * 4096;
    #pragma unroll
    for (int j = 0; j < 4; ++j)
        dma16(xq + c * CK + j * 16, xd + j * 1024);
    unsigned char* bd = s + BOFF + wv * 4096;
    #pragma unroll
    for (int i = 0; i < 4; ++i)
        dma16(wq + (size_t)c * 1024 + i * 64, bd + i * 1024);
}

// ---------------------------------------------------------------------------
// R11: FIFO-aware counted-vmcnt DMA ring (T3+T4). R3-R10 post-mortem: vmcnt
// retires IN ISSUE ORDER, so any wave mixing fast L2 B-loads with slow HBM
// x-loads serializes every step on queued-HBM latency (~1.2us x 64 serial
// steps/CU = the 73-100us plateau, invariant across 7 structures). Fix: ALL
// in-loop vmem is global_load_lds (8/wave/chunk exactly), ring of 4 LDS
// slots, depth-3 prefetch. Body c: s_waitcnt vmcnt(16) [= 3 chunks out -
// oldest done] -> raw s_barrier (no drain; own-wait+barrier => chunk c fully
// staged by all waves) -> issue chunk c+3 -> compute (ds_read only). Waits
// never hit 0 until the tail. 256 blocks (1/CU) x 4 waves; wave = 16 tokens
// x 64 experts x full K. A-layout/read + routing epilogue [R8/R9-verified],
// wimg layout [R3-verified].
// ---------------------------------------------------------------------------
__global__ __launch_bounds__(256, 1) void router_main(
    const float* __restrict__ x, const uint4* __restrict__ wimg,
    float* __restrict__ out, float* __restrict__ zpartial)
{
    __shared__ __align__(16) unsigned char smem[4 * SLOT];   // 128 KB ring
    __shared__ float zred[4];

    const int tid  = threadIdx.x;
    const int wv   = __builtin_amdgcn_readfirstlane(tid >> 6);
    const int lane = tid & 63;
    const int rowr = lane & 15;          // token row within wave tile
    const int kg   = lane >> 4;          // k-group 0..3
    const int t0b  = blockIdx.x * MT;

    // x DMA source: lane (kg,rowr) -> row t0b+wv*16+rowr, 16B piece kg of
    // each 64B slab; per (c,j): + c*64 + j*16 floats.
    const float* xq = x + (size_t)(t0b + wv * 16 + rowr) * HIDDEN + kg * 4;
    // B DMA source: this wave's slot quarter
    const uint4* wq = wimg + wv * 256 + lane;

    f32x4 acc0[4], acc1[4];
    #pragma unroll
    for (int g = 0; g < 4; ++g) { acc0[g] = (f32x4)0.f; acc1[g] = (f32x4)0.f; }

    // prologue: fill depth-3 (24 DMAs outstanding per wave)
    stage_chunk(smem, xq, wq, wv, 0);
    stage_chunk(smem, xq, wq, wv, 1);
    stage_chunk(smem, xq, wq, wv, 2);

    for (int c = 0; c < NCH; ++c) {
        // counted wait: oldest chunk (c) done, newer 2 stay in flight
        if (c < NCH - 2) {
            asm volatile("s_waitcnt vmcnt(16)" ::: "memory");
        } else if (c == NCH - 2) {
            asm volatile("s_waitcnt vmcnt(8)" ::: "memory");
        } else {
            asm volatile("s_waitcnt vmcnt(0)" ::: "memory");
        }
        __builtin_amdgcn_sched_barrier(0);
        asm volatile("s_barrier" ::: "memory");   // raw barrier: NO vmcnt drain
        __builtin_amdgcn_sched_barrier(0);

        if (c + 3 < NCH) stage_chunk(smem, xq, wq, wv, c + 3);

        // ---- compute chunk c: 2 k-steps x (2 A ds_b128 + cvt + 8 B ds_b128
        // + 12 MFMA), all operands from LDS ----
        const unsigned char* s  = smem + (size_t)(c & 3) * SLOT;
        const unsigned char* xw = s + wv * 4096;
        const unsigned char* bw = s + BOFF;
        #pragma unroll
        for (int kh = 0; kh < 2; ++kh) {
            // lane (rowr,kg) needs floats [kh*32+kg*8, +8):
            // slab j0 = 2kh + (kg>>1), pieces (kg&1)*2, (kg&1)*2+1
            const int kb = (2 * kh + (kg >> 1)) * 1024 + (kg & 1) * 512 + rowr * 16;
            const float4 va = *(const float4*)(xw + kb);
            const float4 vb = *(const float4*)(xw + kb + 256);
            f16x8 Ah, Al;
            cvt_split(va, vb, Ah, Al);
            #pragma unroll
            for (int g = 0; g < 4; ++g) {
                const int sh = ((g >> 1) * 512 + kh * 128 + (g & 1) * 64 + lane) * 16;
                const f16x8 bh = *(const f16x8*)(bw + sh);
                const f16x8 bl = *(const f16x8*)(bw + sh + 4096);   // term 1
                acc0[g] = __builtin_amdgcn_mfma_f32_16x16x32_f16(Ah, bh, acc0[g], 0, 0, 0);
                acc1[g] = __builtin_amdgcn_mfma_f32_16x16x32_f16(Ah, bl, acc1[g], 0, 0, 0);
                acc1[g] = __builtin_amdgcn_mfma_f32_16x16x32_f16(Al, bh, acc1[g], 0, 0, 0);
            }
        }
    }

    // ---- in-register routing [R8/R9-verified]: lane group kg routes tokens
    // wv*16 + kg*4 + r; expert e = g*16 + rowr, 4 vals/lane, 16-wide shuffles.
    float zsum = 0.f;
    #pragma unroll
    for (int r = 0; r < 4; ++r) {
        const int t = wv * 16 + kg * 4 + r;
        float v[4]; int e[4];
        #pragma unroll
        for (int g = 0; g < 4; ++g) {
            v[g] = acc0[g][r] + acc1[g][r] * (1.f / 4096.f);
            e[g] = g * 16 + rowr;
        }

        float bv = v[0]; int bi = e[0];
        #pragma unroll
        for (int g = 1; g < 4; ++g)
            if (v[g] > bv) { bv = v[g]; bi = e[g]; }
        #pragma unroll
        for (int st = 1; st < 16; st <<= 1) {
            const float ov = __shfl_xor(bv, st, 64);
            const int   oi = __shfl_xor(bi, st, 64);
            if (ov > bv || (ov == bv && oi < bi)) { bv = ov; bi = oi; }
        }
        const float max1 = bv; const int s1 = bi;

        float e1[4], se = 0.f, sm1 = 0.f;
        #pragma unroll
        for (int g = 0; g < 4; ++g) {
            e1[g] = expf(v[g] - max1);
            se += e1[g];
            const bool m1 = (max1 - v[g]) > 0.02f * fmaxf(fabsf(v[g]), max1);
            sm1 += m1 ? 0.f : e1[g];
        }
        #pragma unroll
        for (int st = 1; st < 16; st <<= 1) {
            se  += __shfl_xor(se, st, 64);
            sm1 += __shfl_xor(sm1, st, 64);
        }

        #pragma unroll
        for (int g = 0; g < 4; ++g)
            out[GATES_OFF + (size_t)(t0b + t) * NEXP + e[g]] = e1[g] / se;

        const float lse = max1 + logf(se);
        if (rowr == 0) zsum += lse * lse;

        float bv2 = (e[0] == s1) ? -INFINITY : v[0]; int bi2 = e[0];
        #pragma unroll
        for (int g = 1; g < 4; ++g) {
            const float cv = (e[g] == s1) ? -INFINITY : v[g];
            if (cv > bv2) { bv2 = cv; bi2 = e[g]; }
        }
        #pragma unroll
        for (int st = 1; st < 16; st <<= 1) {
            const float ov = __shfl_xor(bv2, st, 64);
            const int   oi = __shfl_xor(bi2, st, 64);
            if (ov > bv2 || (ov == bv2 && oi < bi2)) { bv2 = ov; bi2 = oi; }
        }
        const float max2 = bv2; const int s2 = bi2;

        float sm2 = 0.f;
        #pragma unroll
        for (int g = 0; g < 4; ++g) {
            const bool m2 = (max2 - v[g]) > 0.02f * fmaxf(fabsf(v[g]), max2);
            sm2 += (m2 || e[g] == s1) ? 0.f : expf(v[g] - max2);
        }
        #pragma unroll
        for (int st = 1; st < 16; st <<= 1)
            sm2 += __shfl_xor(sm2, st, 64);

        if (rowr == 0) {
            const size_t trow = (size_t)(t0b + t) * 2;
            out[trow + 0] = 1.f / sm1;
            out[trow + 1] = 1.f / sm2;
            out[SEL_OFF + trow + 0] = (float)s1;
            out[SEL_OFF + trow + 1] = (float)s2;
        }
    }

    const float zt = wave_sum64(zsum);
    if (lane == 0) zred[wv] = zt;
    __syncthreads();
    if (tid == 0)
        zpartial[blockIdx.x] = zred[0] + zred[1] + zred[2] + zred[3];
}

__global__ __launch_bounds__(256) void zfinal(
    const float* __restrict__ zpartial, float* __restrict__ out)
{
    const int tid = threadIdx.x;                 // 256 partials, 256 threads
    float v = zpartial[tid];
    v = wave_sum64(v);
    __shared__ float red[4];
    if ((tid & 63) == 0) red[tid >> 6] = v;
    __syncthreads();
    if (tid == 0) {
        const float tot = red[0] + red[1] + red[2] + red[3];
        out[Z_OFF] = 0.001f * (tot / (float)TOKENS);
    }
}

extern "C" void kernel_launch(void* const* d_in, const int* in_sizes, int n_in,
                              void* d_out, int out_size, void* d_ws, size_t ws_size,
                              hipStream_t stream) {
    const float* x = (const float*)d_in[0];   // [16384, 2048] fp32
    const float* w = (const float*)d_in[1];   // [64, 2048] fp32
    float* out = (float*)d_out;               // mult(32768) | gates(1048576) | sel(32768) | z(1)

    uint4* wimg     = (uint4*)d_ws;                               // 512 KB
    float* zpartial = (float*)((char*)d_ws + WIMG_BYTES);         // 256 floats

    wconvert<<<128, 256, 0, stream>>>(w, wimg);
    router_main<<<NBLK, 256, 0, stream>>>(x, wimg, out, zpartial);
    zfinal<<<1, 256, 0, stream>>>(zpartial, out);
}